// Round 5
// baseline (189.792 us; speedup 1.0000x reference)
//
#include <hip/hip_runtime.h>

typedef __attribute__((ext_vector_type(8))) short short8;
typedef __attribute__((ext_vector_type(4))) float f32x4;
typedef __attribute__((ext_vector_type(4))) unsigned short u16x4;

#define B_   4
#define C_   2048
#define HW_  196
#define P_   784      // B_*HW_
#define NCLS 80
#define WD   300
#define ID   1024

// workspace layout (float offsets)
#define WP_OFF    0          // word_p [80][1024]
#define V_OFF     81920      // v [1024]
#define BS_OFF    82944      // bs [1]
#define IMGP_OFF  83968      // img_p partials [4][784][1024]
#define LG_OFF    3295232    // logits [784][80]
#define VPART_OFF 3357952    // vpart [16][1024]
#define SM_OFF    3374336    // softmax [4][80][196]
#define ABF_BYTE  13748224   // Abf [784][2048] bf16
#define WBF_BYTE  16959488   // Wbf [1024][2048] bf16

__device__ __forceinline__ unsigned short f2bf(float x) {
    unsigned u = __float_as_uint(x);
    return (unsigned short)((u + 0x7FFFu + ((u >> 16) & 1u)) >> 16);  // RNE
}

// ---- K_prep: fused independent preprocessing via block-range dispatch ----
__global__ __launch_bounds__(256) void k_prep(const float* __restrict__ img,
                                              const float* __restrict__ wf,
                                              const float* __restrict__ fc1w,
                                              const float* __restrict__ fc2w,
                                              const float* __restrict__ fc3w,
                                              const float* __restrict__ fc4w,
                                              unsigned short* __restrict__ abf,
                                              unsigned short* __restrict__ wbf,
                                              float* __restrict__ wp,
                                              float* __restrict__ vpart) {
    __shared__ unsigned short tile[HW_][68];
    int bid = blockIdx.x, t = threadIdx.x;
    if (bid < 320) {                       // ---- word_p ----
        int idx = bid * 256 + t;
        int n = idx >> 10, d = idx & 1023;
        const float4* a = (const float4*)(wf + n * WD);
        const float4* b = (const float4*)(fc2w + d * WD);
        float s = 0.f;
        #pragma unroll 5
        for (int k = 0; k < WD / 4; ++k) {
            float4 x = a[k], y = b[k];
            s += x.x * y.x + x.y * y.y + x.z * y.z + x.w * y.w;
        }
        wp[idx] = s;
    } else if (bid < 832) {                // ---- cvtW ----
        size_t base = (size_t)(bid - 320) * 4096 + (size_t)t * 16;
        #pragma unroll
        for (int j = 0; j < 4; ++j) {
            float4 v4 = *(const float4*)(fc1w + base + j * 4);
            u16x4 r = {f2bf(v4.x), f2bf(v4.y), f2bf(v4.z), f2bf(v4.w)};
            *(u16x4*)(wbf + base + j * 4) = r;
        }
    } else if (bid < 960) {                // ---- cvtA ----
        int bc = bid - 832;
        int c0 = (bc >> 2) * 64, b = bc & 3;
        for (int idx = t; idx < 64 * HW_; idx += 256) {
            int c = idx / HW_, hw = idx - c * HW_;
            tile[hw][c] = f2bf(img[((size_t)b * C_ + c0 + c) * HW_ + hw]);
        }
        __syncthreads();
        for (int q = t; q < 16 * HW_; q += 256) {
            int hw = q >> 4, c4 = (q & 15) * 4;
            u16x4 r = *(const u16x4*)&tile[hw][c4];
            *(u16x4*)(abf + ((size_t)b * HW_ + hw) * C_ + c0 + c4) = r;
        }
    } else {                               // ---- vpart ----
        int idx = bid - 960;
        int ec = idx >> 2;
        int d = (idx & 3) * 256 + t;
        float s = 0.f;
        #pragma unroll 8
        for (int e = ec * 64; e < ec * 64 + 64; ++e) s += fc4w[e] * fc3w[e * ID + d];
        vpart[ec * ID + d] = s;
    }
}

// ---- K_fc1 v2: LDS-free MFMA GEMM, operands direct from L2 ----
// A-frag: lane reads Abf[p = bx*64+w*16+lr][k + lhi*8]  (16 rows x 64B full lines)
// B-frag: lane reads Wbf[d = by*64+j*16+lr][k + lhi*8]
// block (0,0,0) also finalizes v and bs.
__global__ __launch_bounds__(256) void k_fc1(const unsigned short* __restrict__ Abf,
                                             const unsigned short* __restrict__ Wbf,
                                             const float* __restrict__ fc3b,
                                             const float* __restrict__ fc4w,
                                             const float* __restrict__ fc4b,
                                             const float* __restrict__ vpart,
                                             float* __restrict__ imgp4,
                                             float* __restrict__ v,
                                             float* __restrict__ bs) {
    __shared__ float red[256];
    int t = threadIdx.x;
    int bx = blockIdx.x, by = blockIdx.y, bz = blockIdx.z;
    int w = t >> 6, l = t & 63;
    int lr = l & 15, lhi = l >> 4;

    int pA = bx * 64 + w * 16 + lr;
    int pAc = pA < P_ ? pA : P_ - 1;
    const unsigned short* aBase = Abf + (size_t)pAc * C_ + bz * 512 + lhi * 8;
    const unsigned short* bBase = Wbf + (size_t)(by * 64 + lr) * C_ + bz * 512 + lhi * 8;

    f32x4 acc[4];
    #pragma unroll
    for (int j = 0; j < 4; ++j) acc[j] = (f32x4){0.f, 0.f, 0.f, 0.f};

    #pragma unroll 4
    for (int k2 = 0; k2 < 16; ++k2) {          // 16 steps of K=32
        short8 af = *(const short8*)(aBase + k2 * 32);
        #pragma unroll
        for (int j = 0; j < 4; ++j) {
            short8 bf = *(const short8*)(bBase + (size_t)j * 16 * C_ + k2 * 32);
            acc[j] = __builtin_amdgcn_mfma_f32_16x16x32_bf16(af, bf, acc[j], 0, 0, 0);
        }
    }

    float* outp = imgp4 + (size_t)bz * (P_ * ID);
    int prow = bx * 64 + w * 16 + lhi * 4;
    int dcol = by * 64 + lr;
    #pragma unroll
    for (int j = 0; j < 4; ++j)
        #pragma unroll
        for (int i = 0; i < 4; ++i)
            if (prow + i < P_) outp[(size_t)(prow + i) * ID + dcol + j * 16] = acc[j][i];

    if (bx == 0 && by == 0 && bz == 0) {       // finalize v and bs
        for (int d = t; d < ID; d += 256) {
            float s = 0.f;
            #pragma unroll
            for (int k = 0; k < 16; ++k) s += vpart[k * ID + d];
            v[d] = s;
        }
        float s = 0.f;
        for (int i = t; i < ID; i += 256) s += fc3b[i] * fc4w[i];
        red[t] = s; __syncthreads();
        for (int o = 128; o > 0; o >>= 1) { if (t < o) red[t] += red[t + o]; __syncthreads(); }
        if (t == 0) bs[0] = red[0] + fc4b[0];
    }
}

// ---- K_logits: lg[p][n] = sum_d tanh(imgp[p,d]*wp[n,d])*v[d] + bs ----
// grid (196,4): 4 waves = 4 p's; 20 n per block in 2 LDS chunks of 10 rows (40KB).
__global__ __launch_bounds__(256) void k_logits(const float* __restrict__ imgp4,
                                                const float* __restrict__ wp,
                                                const float* __restrict__ v,
                                                const float* __restrict__ bs,
                                                float* __restrict__ lg) {
    __shared__ float wpl[10 * ID];
    int bx = blockIdx.x, by = blockIdx.y;
    int t = threadIdx.x, wv = t >> 6, lane = t & 63;
    int p = bx * 4 + wv;
    const int S = P_ * ID;
    const float* ap = imgp4 + (size_t)p * ID;
    const float K2 = 2.8853900817779268f;  // 2*log2(e)
    f32x4 a2[4], nv2[4];
    float sv = 0.f;
    #pragma unroll
    for (int q = 0; q < 4; ++q) {
        int d = q * 256 + lane * 4;
        f32x4 aq = *(const f32x4*)(ap + d);
        aq += *(const f32x4*)(ap + S + d);
        aq += *(const f32x4*)(ap + 2 * S + d);
        aq += *(const f32x4*)(ap + 3 * S + d);
        f32x4 vq = *(const f32x4*)(v + d);
        a2[q] = aq * K2;
        nv2[q] = vq * -2.0f;
        sv += vq.x + vq.y + vq.z + vq.w;
    }
    float bsv = bs[0];
    int n0 = by * 20;
    #pragma unroll
    for (int ch = 0; ch < 2; ++ch) {
        __syncthreads();
        #pragma unroll
        for (int j = 0; j < 10; ++j) {         // stage 10 wp rows (40KB)
            int flat = t * 40 + j * 4;
            *(f32x4*)(wpl + flat) =
                *(const f32x4*)(wp + (size_t)(n0 + ch * 10 + (flat >> 10)) * ID + (flat & 1023));
        }
        __syncthreads();
        #pragma unroll 2
        for (int r = 0; r < 10; ++r) {
            float s = sv;
            #pragma unroll
            for (int q = 0; q < 4; ++q) {
                f32x4 wq = *(const f32x4*)(wpl + r * ID + q * 256 + lane * 4);
                float e0 = __builtin_amdgcn_exp2f(a2[q].x * wq.x);
                float e1 = __builtin_amdgcn_exp2f(a2[q].y * wq.y);
                float e2 = __builtin_amdgcn_exp2f(a2[q].z * wq.z);
                float e3 = __builtin_amdgcn_exp2f(a2[q].w * wq.w);
                s += nv2[q].x * __builtin_amdgcn_rcpf(e0 + 1.f);
                s += nv2[q].y * __builtin_amdgcn_rcpf(e1 + 1.f);
                s += nv2[q].z * __builtin_amdgcn_rcpf(e2 + 1.f);
                s += nv2[q].w * __builtin_amdgcn_rcpf(e3 + 1.f);
            }
            #pragma unroll
            for (int off = 32; off > 0; off >>= 1) s += __shfl_xor(s, off, 64);
            if (lane == 0) lg[p * NCLS + n0 + ch * 10 + r] = s + bsv;
        }
    }
}

// ---- K_softmax: softmax over 196 positions per (b,n) -> sm[b][n][hw] ----
__global__ __launch_bounds__(256) void k_softmax(const float* __restrict__ lg,
                                                 float* __restrict__ sm) {
    __shared__ float red[256];
    int b = blockIdx.x, n = blockIdx.y, t = threadIdx.x;
    float x = (t < HW_) ? lg[(size_t)(b * HW_ + t) * NCLS + n] : -1e30f;
    red[t] = x; __syncthreads();
    for (int o = 128; o > 0; o >>= 1) { if (t < o) red[t] = fmaxf(red[t], red[t + o]); __syncthreads(); }
    float mx = red[0]; __syncthreads();
    float e = (t < HW_) ? __expf(x - mx) : 0.f;
    red[t] = e; __syncthreads();
    for (int o = 128; o > 0; o >>= 1) { if (t < o) red[t] += red[t + o]; __syncthreads(); }
    float inv = __builtin_amdgcn_rcpf(red[0]);
    if (t < HW_) sm[((size_t)b * NCLS + n) * HW_ + t] = e * inv;
}

// ---- K_pool v2: out[b,n,c] = sum_hw sm[b,n,hw]*img[b,c,hw] ----
// sm read via wave-uniform pointers -> scalar loads (parallel to v_fmac stream); no LDS.
__global__ __launch_bounds__(256) void k_pool(const float* __restrict__ sm,
                                              const float* __restrict__ img,
                                              float* __restrict__ out) {
    int cb = blockIdx.x, nt = blockIdx.y, b = blockIdx.z, t = threadIdx.x;
    int c = cb * 256 + t;
    const float* row = img + ((size_t)b * C_ + c) * HW_;
    const float* smb = sm + ((size_t)b * NCLS + nt * 16) * HW_;
    float acc[16] = {};
    for (int h4 = 0; h4 < HW_ / 4; ++h4) {
        float4 iv = *(const float4*)(row + h4 * 4);
        #pragma unroll
        for (int nl = 0; nl < 16; ++nl) {
            float4 s4 = *(const float4*)(smb + nl * HW_ + h4 * 4);   // uniform -> s_load
            acc[nl] += iv.x * s4.x + iv.y * s4.y + iv.z * s4.z + iv.w * s4.w;
        }
    }
    #pragma unroll
    for (int nl = 0; nl < 16; ++nl)
        out[((size_t)b * NCLS + nt * 16 + nl) * C_ + c] = acc[nl];
}

extern "C" void kernel_launch(void* const* d_in, const int* in_sizes, int n_in,
                              void* d_out, int out_size, void* d_ws, size_t ws_size,
                              hipStream_t stream) {
    const float* img  = (const float*)d_in[0];
    const float* wf   = (const float*)d_in[1];
    const float* fc1w = (const float*)d_in[2];
    const float* fc2w = (const float*)d_in[3];
    const float* fc3w = (const float*)d_in[4];
    const float* fc3b = (const float*)d_in[5];
    const float* fc4w = (const float*)d_in[6];
    const float* fc4b = (const float*)d_in[7];
    float* out = (float*)d_out;
    float* ws  = (float*)d_ws;

    float* wp    = ws + WP_OFF;
    float* v     = ws + V_OFF;
    float* bs    = ws + BS_OFF;
    float* imgp4 = ws + IMGP_OFF;
    float* lg    = ws + LG_OFF;
    float* vpart = ws + VPART_OFF;
    float* sm    = ws + SM_OFF;
    unsigned short* Abf = (unsigned short*)((char*)d_ws + ABF_BYTE);
    unsigned short* Wbf = (unsigned short*)((char*)d_ws + WBF_BYTE);

    k_prep   <<<dim3(1024),      256, 0, stream>>>(img, wf, fc1w, fc2w, fc3w, fc4w,
                                                   Abf, Wbf, wp, vpart);
    k_fc1    <<<dim3(13, 16, 4), 256, 0, stream>>>(Abf, Wbf, fc3b, fc4w, fc4b, vpart,
                                                   imgp4, v, bs);
    k_logits <<<dim3(196, 4),    256, 0, stream>>>(imgp4, wp, v, bs, lg);
    k_softmax<<<dim3(4, 80),     256, 0, stream>>>(lg, sm);
    k_pool   <<<dim3(8, 5, 4),   256, 0, stream>>>(sm, img, out);
}

// Round 7
// 161.369 us; speedup vs baseline: 1.1761x; 1.1761x over previous
//
#include <hip/hip_runtime.h>

typedef __attribute__((ext_vector_type(8))) short short8;
typedef __attribute__((ext_vector_type(4))) float f32x4;
typedef __attribute__((ext_vector_type(4))) unsigned short u16x4;

#define B_   4
#define C_   2048
#define HW_  196
#define P_   784      // B_*HW_
#define NCLS 80
#define WD   300
#define ID   1024

// workspace layout (float offsets)
#define WP_OFF    0          // word_p [80][1024]
#define V_OFF     81920      // v [1024]
#define BS_OFF    82944      // bs [1]
#define IMGP_OFF  83968      // img_p partials [4][784][1024]
#define LG_OFF    3295232    // logits [784][80]
#define VPART_OFF 3357952    // vpart [16][1024]
#define ABF_BYTE  13748224   // Abf [784][2048] bf16
#define WBF_BYTE  16959488   // Wbf [1024][2048] bf16

__device__ __forceinline__ unsigned short f2bf(float x) {
    unsigned u = __float_as_uint(x);
    return (unsigned short)((u + 0x7FFFu + ((u >> 16) & 1u)) >> 16);  // RNE
}

// ---- K_prep: fused independent preprocessing via block-range dispatch ----
// [0,320) word_p | [320,832) cvtW | [832,960) cvtA | [960,1024) vpart
__global__ __launch_bounds__(256) void k_prep(const float* __restrict__ img,
                                              const float* __restrict__ wf,
                                              const float* __restrict__ fc1w,
                                              const float* __restrict__ fc2w,
                                              const float* __restrict__ fc3w,
                                              const float* __restrict__ fc4w,
                                              unsigned short* __restrict__ abf,
                                              unsigned short* __restrict__ wbf,
                                              float* __restrict__ wp,
                                              float* __restrict__ vpart) {
    __shared__ unsigned short tile[HW_][68];
    int bid = blockIdx.x, t = threadIdx.x;
    if (bid < 320) {                       // ---- word_p ----
        int idx = bid * 256 + t;
        int n = idx >> 10, d = idx & 1023;
        const float4* a = (const float4*)(wf + n * WD);
        const float4* b = (const float4*)(fc2w + d * WD);
        float s = 0.f;
        #pragma unroll 5
        for (int k = 0; k < WD / 4; ++k) {
            float4 x = a[k], y = b[k];
            s += x.x * y.x + x.y * y.y + x.z * y.z + x.w * y.w;
        }
        wp[idx] = s;
    } else if (bid < 832) {                // ---- cvtW ----
        size_t base = (size_t)(bid - 320) * 4096 + (size_t)t * 16;
        #pragma unroll
        for (int j = 0; j < 4; ++j) {
            float4 v4 = *(const float4*)(fc1w + base + j * 4);
            u16x4 r = {f2bf(v4.x), f2bf(v4.y), f2bf(v4.z), f2bf(v4.w)};
            *(u16x4*)(wbf + base + j * 4) = r;
        }
    } else if (bid < 960) {                // ---- cvtA ----
        int bc = bid - 832;
        int c0 = (bc >> 2) * 64, b = bc & 3;
        for (int idx = t; idx < 64 * HW_; idx += 256) {
            int c = idx / HW_, hw = idx - c * HW_;
            tile[hw][c] = f2bf(img[((size_t)b * C_ + c0 + c) * HW_ + hw]);
        }
        __syncthreads();
        for (int q = t; q < 16 * HW_; q += 256) {
            int hw = q >> 4, c4 = (q & 15) * 4;
            u16x4 r = *(const u16x4*)&tile[hw][c4];
            *(u16x4*)(abf + ((size_t)b * HW_ + hw) * C_ + c0 + c4) = r;
        }
    } else {                               // ---- vpart ----
        int idx = bid - 960;
        int ec = idx >> 2;
        int d = (idx & 3) * 256 + t;
        float s = 0.f;
        #pragma unroll 8
        for (int e = ec * 64; e < ec * 64 + 64; ++e) s += fc4w[e] * fc3w[e * ID + d];
        vpart[ec * ID + d] = s;
    }
}

// ---- K_fc1 (round-4 proven form): split-K=4 bf16 MFMA, LDS double-buffered ----
// block (0,0,0) also finalizes v = sum vpart and bs = fc3b.fc4w + fc4b.
#define LDT 72
__global__ __launch_bounds__(256) void k_fc1(const unsigned short* __restrict__ Abf,
                                             const unsigned short* __restrict__ Wbf,
                                             const float* __restrict__ fc3b,
                                             const float* __restrict__ fc4w,
                                             const float* __restrict__ fc4b,
                                             const float* __restrict__ vpart,
                                             float* __restrict__ imgp4,
                                             float* __restrict__ v,
                                             float* __restrict__ bs) {
    __shared__ unsigned short As[2][64 * LDT];
    __shared__ unsigned short Bs[2][64 * LDT];
    int t = threadIdx.x;
    int bx = blockIdx.x, by = blockIdx.y, bz = blockIdx.z;
    int w = t >> 6, l = t & 63;
    int lr = l & 15, lhi = l >> 4;
    int row = t >> 2, cq = (t & 3) * 16;

    int pA = bx * 64 + row;
    int pAc = pA < P_ ? pA : P_ - 1;
    const unsigned short* aBase = Abf + (size_t)pAc * C_ + bz * 512 + cq;
    const unsigned short* bBase = Wbf + (size_t)(by * 64 + row) * C_ + bz * 512 + cq;

    short8 ra0, ra1, rb0, rb1;
    f32x4 acc[4];
    #pragma unroll
    for (int j = 0; j < 4; ++j) acc[j] = (f32x4){0.f, 0.f, 0.f, 0.f};

    #define LOADR(kc) { \
        const short8* ap = (const short8*)(aBase + (kc) * 64); \
        const short8* bp = (const short8*)(bBase + (kc) * 64); \
        ra0 = ap[0]; ra1 = ap[1]; rb0 = bp[0]; rb1 = bp[1]; }
    #define WRITES(buf) { \
        *(short8*)&As[buf][row * LDT + cq]     = ra0; \
        *(short8*)&As[buf][row * LDT + cq + 8] = ra1; \
        *(short8*)&Bs[buf][row * LDT + cq]     = rb0; \
        *(short8*)&Bs[buf][row * LDT + cq + 8] = rb1; }

    LOADR(0);
    WRITES(0);
    __syncthreads();

    for (int kc = 0; kc < 8; ++kc) {
        int cur = kc & 1;
        if (kc < 7) LOADR(kc + 1);
        #pragma unroll
        for (int kk = 0; kk < 2; ++kk) {
            short8 af = *reinterpret_cast<const short8*>(
                &As[cur][(w * 16 + lr) * LDT + kk * 32 + lhi * 8]);
            #pragma unroll
            for (int j = 0; j < 4; ++j) {
                short8 bfr = *reinterpret_cast<const short8*>(
                    &Bs[cur][(j * 16 + lr) * LDT + kk * 32 + lhi * 8]);
                acc[j] = __builtin_amdgcn_mfma_f32_16x16x32_bf16(af, bfr, acc[j], 0, 0, 0);
            }
        }
        if (kc < 7) WRITES(cur ^ 1);
        __syncthreads();
    }
    #undef LOADR
    #undef WRITES

    float* outp = imgp4 + (size_t)bz * (P_ * ID);
    int prow = bx * 64 + w * 16 + lhi * 4;
    int dcol = by * 64 + lr;
    #pragma unroll
    for (int j = 0; j < 4; ++j)
        #pragma unroll
        for (int i = 0; i < 4; ++i)
            if (prow + i < P_) outp[(size_t)(prow + i) * ID + dcol + j * 16] = acc[j][i];

    if (bx == 0 && by == 0 && bz == 0) {   // finalize v and bs
        for (int d = t; d < ID; d += 256) {
            float s = 0.f;
            #pragma unroll
            for (int k = 0; k < 16; ++k) s += vpart[k * ID + d];
            v[d] = s;
        }
        float s = 0.f;
        for (int i = t; i < ID; i += 256) s += fc3b[i] * fc4w[i];
        __syncthreads();
        float* red = (float*)&As[0][0];
        red[t] = s; __syncthreads();
        for (int o = 128; o > 0; o >>= 1) { if (t < o) red[t] += red[t + o]; __syncthreads(); }
        if (t == 0) bs[0] = red[0] + fc4b[0];
    }
}

// ---- K_logits: lg[p][n] = sum_d tanh(imgp[p,d]*wp[n,d])*v[d] + bs ----
// grid (196,4): 4 waves = 4 p's; 20 n per block in 2 LDS chunks of 10 rows.
// Staging is a FLAT contiguous copy (10 consecutive wp rows) -> conflict-free,
// fully coalesced (round-4/5 version had a ~32-way ds_write bank conflict).
__global__ __launch_bounds__(256) void k_logits(const float* __restrict__ imgp4,
                                                const float* __restrict__ wp,
                                                const float* __restrict__ v,
                                                const float* __restrict__ bs,
                                                float* __restrict__ lg) {
    __shared__ float wpl[10 * ID];
    int bx = blockIdx.x, by = blockIdx.y;
    int t = threadIdx.x, wv = t >> 6, lane = t & 63;
    int p = bx * 4 + wv;
    const int S = P_ * ID;
    const float* ap = imgp4 + (size_t)p * ID;
    const float K2 = 2.8853900817779268f;  // 2*log2(e)
    f32x4 a2[4], nv2[4];
    float sv = 0.f;
    #pragma unroll
    for (int q = 0; q < 4; ++q) {
        int d = q * 256 + lane * 4;
        f32x4 aq = *(const f32x4*)(ap + d);
        aq += *(const f32x4*)(ap + S + d);
        aq += *(const f32x4*)(ap + 2 * S + d);
        aq += *(const f32x4*)(ap + 3 * S + d);
        f32x4 vq = *(const f32x4*)(v + d);
        a2[q] = aq * K2;
        nv2[q] = vq * -2.0f;
        sv += vq.x + vq.y + vq.z + vq.w;
    }
    float bsv = bs[0];
    int n0 = by * 20;
    #pragma unroll
    for (int ch = 0; ch < 2; ++ch) {
        const float* src = wp + (size_t)(n0 + ch * 10) * ID;   // 10 contiguous rows
        __syncthreads();
        #pragma unroll
        for (int k = 0; k < 10; ++k)
            *(f32x4*)(wpl + k * ID + t * 4) = *(const f32x4*)(src + k * ID + t * 4);
        __syncthreads();
        #pragma unroll 2
        for (int r = 0; r < 10; ++r) {
            float s = sv;
            #pragma unroll
            for (int q = 0; q < 4; ++q) {
                f32x4 wq = *(const f32x4*)(wpl + r * ID + q * 256 + lane * 4);
                float e0 = __builtin_amdgcn_exp2f(a2[q].x * wq.x);
                float e1 = __builtin_amdgcn_exp2f(a2[q].y * wq.y);
                float e2 = __builtin_amdgcn_exp2f(a2[q].z * wq.z);
                float e3 = __builtin_amdgcn_exp2f(a2[q].w * wq.w);
                s += nv2[q].x * __builtin_amdgcn_rcpf(e0 + 1.f);
                s += nv2[q].y * __builtin_amdgcn_rcpf(e1 + 1.f);
                s += nv2[q].z * __builtin_amdgcn_rcpf(e2 + 1.f);
                s += nv2[q].w * __builtin_amdgcn_rcpf(e3 + 1.f);
            }
            #pragma unroll
            for (int off = 32; off > 0; off >>= 1) s += __shfl_xor(s, off, 64);
            if (lane == 0) lg[p * NCLS + n0 + ch * 10 + r] = s + bsv;
        }
    }
}

// ---- K_pool (round-4 proven form): fused softmax + weighted pooling ----
__global__ __launch_bounds__(256) void k_pool(const float* __restrict__ lg,
                                              const float* __restrict__ img,
                                              float* __restrict__ out) {
    __shared__ float smt[16 * HW_];
    int cb = blockIdx.x, nt = blockIdx.y, b = blockIdx.z, t = threadIdx.x;
    int n_l = t >> 4, seg = t & 15;
    int n = nt * 16 + n_l;
    float xr[13];
    float mx = -1e30f;
    #pragma unroll
    for (int j = 0; j < 13; ++j) {
        int hw = seg + j * 16;
        float x = (hw < HW_) ? lg[(size_t)(b * HW_ + hw) * NCLS + n] : -1e30f;
        xr[j] = x; mx = fmaxf(mx, x);
    }
    #pragma unroll
    for (int o = 8; o > 0; o >>= 1) mx = fmaxf(mx, __shfl_xor(mx, o, 16));
    float sum = 0.f;
    #pragma unroll
    for (int j = 0; j < 13; ++j) {
        int hw = seg + j * 16;
        float e = (hw < HW_) ? __expf(xr[j] - mx) : 0.f;
        xr[j] = e; sum += e;
    }
    #pragma unroll
    for (int o = 8; o > 0; o >>= 1) sum += __shfl_xor(sum, o, 16);
    float inv = __builtin_amdgcn_rcpf(sum);
    #pragma unroll
    for (int j = 0; j < 13; ++j) {
        int hw = seg + j * 16;
        if (hw < HW_) smt[n_l * HW_ + hw] = xr[j] * inv;
    }
    __syncthreads();

    int c = cb * 256 + t;
    const float* row = img + ((size_t)b * C_ + c) * HW_;
    float acc[16] = {};
    for (int h4 = 0; h4 < HW_ / 4; ++h4) {
        float4 iv = *(const float4*)(row + h4 * 4);
        #pragma unroll
        for (int nl = 0; nl < 16; ++nl) {
            float4 s4 = *(const float4*)&smt[nl * HW_ + h4 * 4];
            acc[nl] += iv.x * s4.x + iv.y * s4.y + iv.z * s4.z + iv.w * s4.w;
        }
    }
    #pragma unroll
    for (int nl = 0; nl < 16; ++nl)
        out[((size_t)b * NCLS + nt * 16 + nl) * C_ + c] = acc[nl];
}

extern "C" void kernel_launch(void* const* d_in, const int* in_sizes, int n_in,
                              void* d_out, int out_size, void* d_ws, size_t ws_size,
                              hipStream_t stream) {
    const float* img  = (const float*)d_in[0];
    const float* wf   = (const float*)d_in[1];
    const float* fc1w = (const float*)d_in[2];
    const float* fc2w = (const float*)d_in[3];
    const float* fc3w = (const float*)d_in[4];
    const float* fc3b = (const float*)d_in[5];
    const float* fc4w = (const float*)d_in[6];
    const float* fc4b = (const float*)d_in[7];
    float* out = (float*)d_out;
    float* ws  = (float*)d_ws;

    float* wp    = ws + WP_OFF;
    float* v     = ws + V_OFF;
    float* bs    = ws + BS_OFF;
    float* imgp4 = ws + IMGP_OFF;
    float* lg    = ws + LG_OFF;
    float* vpart = ws + VPART_OFF;
    unsigned short* Abf = (unsigned short*)((char*)d_ws + ABF_BYTE);
    unsigned short* Wbf = (unsigned short*)((char*)d_ws + WBF_BYTE);

    k_prep   <<<dim3(1024),      256, 0, stream>>>(img, wf, fc1w, fc2w, fc3w, fc4w,
                                                   Abf, Wbf, wp, vpart);
    k_fc1    <<<dim3(13, 16, 4), 256, 0, stream>>>(Abf, Wbf, fc3b, fc4w, fc4b, vpart,
                                                   imgp4, v, bs);
    k_logits <<<dim3(196, 4),    256, 0, stream>>>(imgp4, wp, v, bs, lg);
    k_pool   <<<dim3(8, 5, 4),   256, 0, stream>>>(lg, img, out);
}